// Round 15
// baseline (287.303 us; speedup 1.0000x reference)
//
#include <hip/hip_runtime.h>
#include <hip/hip_bf16.h>

// GNN attention layer. V=50000, E=800000, D=H=128. Inputs f32, OUTPUT f32.
//
// R15 on R14 (266 us, agg_proj top at 60 us / 2.05 TB/s / 4-deep gather):
//  - agg_proj: 8 gathers in flight (latency-bound; 2x MLP).
//  - hist moved into the conv launch (hist only needs dst; overlaps streaming).
//    counts zeroed in the probe launch (avoids intra-launch race).
//  - pd/ps fused with scan_a (one launch fewer, mutual overlap).
// Chain: probe+zero -> conv+hist -> pdps+scan_a -> scan_b -> scan_c ->
//        scatter -> agg_proj -> gru.   Rest identical to R14.

#define V_NODES 50000
#define E_EDGES 800000
#define D_FEAT  128
#define NTILE   3125          // V/16
#define SCAN_BLOCKS 196       // ceil(50000/256)
#define GCHUNK  5             // tiles per wave-task (gru, pd/ps)
#define NP_TASKS 625
#define NPW_BLOCKS 157        // ceil(625/4)
#define HIST_BLOCKS 3125      // 800000/256
#define WS_BLOCKS 1250        // gru: 5000 wave-tasks / 4 per block
#define AGG_STRIDE 132        // LDS row stride (elements)

typedef short bf16x8 __attribute__((ext_vector_type(8)));  // 8 bf16 in 4 VGPRs
typedef float f32x4  __attribute__((ext_vector_type(4)));
typedef unsigned short u16x4 __attribute__((ext_vector_type(4)));

// small-tensor bf16 pool element offsets
#define OFF_WEDGE 0
#define OFF_WPROJ 256
#define OFF_WIH   16640
#define OFF_WHH   65792
#define OFF_BEDGE 114944
#define OFF_BPROJ 114945
#define OFF_BIH   115073
#define OFF_BHH   115457
#define SMALL_TOTAL 115841
#define CONV_X_BLOCKS   6250   // 1.6M u16x4 / 256
#define CONV_S_BLOCKS   453

// ---- device-global scratch (~27 MB; immune to ws_size) ----
__device__ int   g_is_bf16;
__device__ float g_pd[V_NODES];
__device__ float g_ps[V_NODES];
__device__ int   g_counts[V_NODES];
__device__ int   g_row_off[V_NODES + 1];
__device__ int   g_blocksum[SCAN_BLOCKS];
__device__ int   g_blockoff[SCAN_BLOCKS];
__device__ int   g_rank[E_EDGES];
__device__ __attribute__((aligned(16))) int2 g_s_pair[E_EDGES];  // {src, bits(w)}
__device__ __attribute__((aligned(16))) unsigned short g_xbf[V_NODES * D_FEAT];
__device__ __attribute__((aligned(16))) unsigned short g_ctx[V_NODES * D_FEAT];
__device__ __attribute__((aligned(16))) unsigned short g_wsmall[SMALL_TOTAL + 15];

static __device__ __forceinline__ float b2f(unsigned short u) {
  union { unsigned int i; float f; } v; v.i = ((unsigned int)u) << 16; return v.f;
}
static __device__ __forceinline__ unsigned short f2b(float f) {
  unsigned int i = __float_as_uint(f);
  unsigned int r = (i + 0x7FFFu + ((i >> 16) & 1u)) >> 16;  // RNE (NaN stays NaN)
  return (unsigned short)r;
}
static __device__ __forceinline__ bf16x8 load_frag(const unsigned short* p) {
  return *reinterpret_cast<const bf16x8*>(p);  // 16B-aligned vector load
}
static __device__ __forceinline__ bf16x8 lds_frag(const unsigned short* p) {
  const uint2 lo = *reinterpret_cast<const uint2*>(p);
  const uint2 hi = *reinterpret_cast<const uint2*>(p + 4);
  uint4 u; u.x = lo.x; u.y = lo.y; u.z = hi.x; u.w = hi.y;
  return __builtin_bit_cast(bf16x8, u);
}

// ---------------- L1: probe dtype (block 0) + zero counts (blocks 1..) -------
__global__ void probe_zero_kernel(const unsigned int* __restrict__ x)
{
  if (blockIdx.x == 0) {
    __shared__ int cnt;
    if (threadIdx.x == 0) cnt = 0;
    __syncthreads();
    const unsigned int w  = x[threadIdx.x];
    const unsigned int lo = w & 0xFFFFu;
    const unsigned int ex = (lo >> 7) & 0xFFu;
    if (lo != 0u && ex >= 118u && ex <= 132u) atomicAdd(&cnt, 1);
    __syncthreads();
    if (threadIdx.x == 0) g_is_bf16 = (cnt >= 200) ? 1 : 0;
  } else {
    const int i = (blockIdx.x - 1) * 256 + threadIdx.x;
    if (i < V_NODES) g_counts[i] = 0;
  }
}

// ---------------- L2: convert-x | convert-smalls | histogram(rank) -----------
__global__ void conv_hist_kernel(
    const void* __restrict__ x, const int* __restrict__ dst,
    const void* p0, const void* p1, const void* p2, const void* p3,
    const void* p4, const void* p5, const void* p6, const void* p7)
{
  const int b = blockIdx.x;
  if (b < CONV_X_BLOCKS) {
    const int t = b * 256 + threadIdx.x;
    if (g_is_bf16) {
      reinterpret_cast<u16x4*>(g_xbf)[t] = reinterpret_cast<const u16x4*>(x)[t];
    } else {
      const float4 v = reinterpret_cast<const float4*>(x)[t];
      u16x4 o; o.x = f2b(v.x); o.y = f2b(v.y); o.z = f2b(v.z); o.w = f2b(v.w);
      reinterpret_cast<u16x4*>(g_xbf)[t] = o;
    }
  } else if (b < CONV_X_BLOCKS + CONV_S_BLOCKS) {
    const int i = (b - CONV_X_BLOCKS) * 256 + threadIdx.x;
    if (i >= SMALL_TOTAL) return;
    const int offs[9] = {OFF_WEDGE, OFF_WPROJ, OFF_WIH, OFF_WHH,
                         OFF_BEDGE, OFF_BPROJ, OFF_BIH, OFF_BHH, SMALL_TOTAL};
    const void* ps[8] = {p0, p1, p2, p3, p4, p5, p6, p7};
    int r = 0;
#pragma unroll
    for (int k = 0; k < 8; k++) if (i >= offs[k]) r = k;
    const int j = i - offs[r];
    g_wsmall[i] = g_is_bf16
        ? reinterpret_cast<const unsigned short*>(ps[r])[j]
        : f2b(reinterpret_cast<const float*>(ps[r])[j]);
  } else {
    const int e = (b - CONV_X_BLOCKS - CONV_S_BLOCKS) * 256 + threadIdx.x;
    if (e < E_EDGES) g_rank[e] = atomicAdd(&g_counts[dst[e]], 1);
  }
}

// ---------------- L3: pd/ps (blocks 0..156) + scan_a (rest) ------------------
__global__ __launch_bounds__(256, 2) void pdps_scan_a_kernel()
{
  const int b = blockIdx.x;
  if (b >= NPW_BLOCKS) {                     // ---- scan_a part ----
    __shared__ int lds[256];
    const int sb = b - NPW_BLOCKS, t = threadIdx.x;
    const int idx = sb * 256 + t;
    const int v = (idx < V_NODES) ? g_counts[idx] : 0;
    lds[t] = v;
    __syncthreads();
    for (int off = 1; off < 256; off <<= 1) {
      int tmp = (t >= off) ? lds[t - off] : 0;
      __syncthreads();
      lds[t] += tmp;
      __syncthreads();
    }
    if (idx < V_NODES) g_row_off[idx] = lds[t] - v;
    if (t == 255) g_blocksum[sb] = lds[255];
    return;
  }
  // ---- pd/ps part ----
  const int g    = b * 4 + (threadIdx.x >> 6);
  if (g >= NP_TASKS) return;
  const int lane = threadIdx.x & 63;
  const int col  = lane & 15;
  const int quad = lane >> 4;

  bf16x8 be[4];
#pragma unroll
  for (int kk = 0; kk < 4; kk++) { be[kk] = bf16x8{0,0,0,0,0,0,0,0}; }
  if (col < 2) {
#pragma unroll
    for (int kk = 0; kk < 4; kk++)
      be[kk] = load_frag(g_wsmall + OFF_WEDGE + col * D_FEAT + kk * 32 + quad * 8);
  }
  const int t0 = g * GCHUNK;
  for (int t = t0; t < t0 + GCHUNK; t++) {
    const int arow = t * 16 + col;
    bf16x8 a[4];
#pragma unroll
    for (int kk = 0; kk < 4; kk++)
      a[kk] = load_frag(g_xbf + arow * D_FEAT + kk * 32 + quad * 8);
    f32x4 acce; acce[0]=0.f; acce[1]=0.f; acce[2]=0.f; acce[3]=0.f;
#pragma unroll
    for (int kk = 0; kk < 4; kk++)
      acce = __builtin_amdgcn_mfma_f32_16x16x32_bf16(a[kk], be[kk], acce, 0, 0, 0);
    if (col == 0) {
#pragma unroll
      for (int r = 0; r < 4; r++) g_pd[t * 16 + quad * 4 + r] = acce[r];
    } else if (col == 1) {
#pragma unroll
      for (int r = 0; r < 4; r++) g_ps[t * 16 + quad * 4 + r] = acce[r];
    }
  }
}

// ---------------- L4: scan the 196 block totals ------------------------------
__global__ __launch_bounds__(256) void scan_b_kernel()
{
  __shared__ int lds[256];
  const int t = threadIdx.x;
  const int v = (t < SCAN_BLOCKS) ? g_blocksum[t] : 0;
  lds[t] = v;
  __syncthreads();
  for (int off = 1; off < 256; off <<= 1) {
    int tmp = (t >= off) ? lds[t - off] : 0;
    __syncthreads();
    lds[t] += tmp;
    __syncthreads();
  }
  if (t < SCAN_BLOCKS) g_blockoff[t] = lds[t] - v;
  if (t == 255) g_row_off[V_NODES] = lds[255];      // total = E
}

// ---------------- L5: add block offsets --------------------------------------
__global__ __launch_bounds__(256) void scan_c_kernel()
{
  const int b = blockIdx.x, t = threadIdx.x;
  const int idx = b * 256 + t;
  if (idx >= V_NODES) return;
  g_row_off[idx] += g_blockoff[b];
}

// ---------------- L6: edge scatter — atomic-free, one 8B write/edge ----------
__global__ void edge_scatter_kernel(
    const int* __restrict__ src, const int* __restrict__ dst, int E)
{
  int e = blockIdx.x * blockDim.x + threadIdx.x;
  if (e >= E) return;
  const int d = dst[e], sn = src[e];
  float logit = g_pd[d] + g_ps[sn] + b2f(g_wsmall[OFF_BEDGE]);
  logit = (logit >= 0.f) ? logit : 0.01f * logit;           // LeakyReLU(0.01)
  const float w = __expf(logit);                            // no max-sub: cancels
  const int pos = g_row_off[d] + g_rank[e];
  g_s_pair[pos] = make_int2(sn, __float_as_int(w));
}

// ---------------- L7: aggregate (node/wave, 8-deep) + proj + elu -> ctx ------
__global__ __launch_bounds__(1024) void agg_proj_kernel()
{
  __shared__ unsigned short s_agg[16 * AGG_STRIDE];   // 4224 B
  __shared__ int s_empty[16];
  const int wave = threadIdx.x >> 6;                  // 16 waves = 16 nodes
  const int lane = threadIdx.x & 63;
  const int tile = blockIdx.x;                        // 16-node tile, [0,3125)

  // ---- phase 1: softmax-weighted x-gather, ONE node per wave, 8 in flight ---
  {
    const int v = tile * 16 + wave;
    const int beg = g_row_off[v], end = g_row_off[v + 1];
    float accx = 0.f, accy = 0.f, ssum = 0.f;
    int i = beg;
    for (; i + 8 <= end; i += 8) {
      int2 q[8];
#pragma unroll
      for (int u = 0; u < 8; u++) q[u] = g_s_pair[i + u];
      unsigned int p[8];
#pragma unroll
      for (int u = 0; u < 8; u++)
        p[u] = *reinterpret_cast<const unsigned int*>(g_xbf + q[u].x * D_FEAT + lane * 2);
#pragma unroll
      for (int u = 0; u < 8; u++) {
        const float w = __int_as_float(q[u].y);
        ssum += w;
        accx += w * b2f((unsigned short)(p[u] & 0xFFFFu));
        accy += w * b2f((unsigned short)(p[u] >> 16));
      }
    }
    for (; i < end; i++) {
      const int2 q = g_s_pair[i];
      const float w = __int_as_float(q.y);
      ssum += w;
      const unsigned int pair =
          *reinterpret_cast<const unsigned int*>(g_xbf + q.x * D_FEAT + lane * 2);
      accx += w * b2f((unsigned short)(pair & 0xFFFFu));
      accy += w * b2f((unsigned short)(pair >> 16));
    }
    const float inv = (end > beg) ? (1.0f / ssum) : 0.0f;
    const unsigned int packed =
        ((unsigned int)f2b(accy * inv) << 16) | (unsigned int)f2b(accx * inv);
    *reinterpret_cast<unsigned int*>(s_agg + wave * AGG_STRIDE + lane * 2) = packed;
    if (lane == 0) s_empty[wave] = (end > beg) ? 0 : 1;
  }
  __syncthreads();

  // ---- phase 2: ctx = elu(agg @ Wproj.T + b_proj); waves 0..7, one cg each --
  if (wave < 8) {
    const int col  = lane & 15;
    const int quad = lane >> 4;
    bf16x8 a[4];
#pragma unroll
    for (int kk = 0; kk < 4; kk++)
      a[kk] = lds_frag(s_agg + col * AGG_STRIDE + kk * 32 + quad * 8);
    const int h  = 16 * wave + col;
    const float bp = b2f(g_wsmall[OFF_BPROJ + h]);
    f32x4 acc; acc[0]=bp; acc[1]=bp; acc[2]=bp; acc[3]=bp;
#pragma unroll
    for (int kk = 0; kk < 4; kk++) {
      bf16x8 bw = load_frag(g_wsmall + OFF_WPROJ + h * D_FEAT + kk * 32 + quad * 8);
      acc = __builtin_amdgcn_mfma_f32_16x16x32_bf16(a[kk], bw, acc, 0, 0, 0);
    }
#pragma unroll
    for (int r = 0; r < 4; r++) {
      const int n = quad * 4 + r;
      float v = acc[r];
      v = (v > 0.f) ? v : (__expf(v) - 1.f);            // elu
      if (s_empty[n]) v = 0.f;                          // empty segment -> ctx 0
      g_ctx[(tile * 16 + n) * D_FEAT + h] = f2b(v);
    }
  }
}

// ---------------- L8: GRU weight-stationary (bf16 residual) ------------------
__global__ __launch_bounds__(256, 2) void gru_kernel(float* __restrict__ out)
{
  const int g     = blockIdx.x * 4 + (threadIdx.x >> 6);
  const int lane  = threadIdx.x & 63;
  const int cg    = g & 7;
  const int chunk = g >> 3;                  // [0, 625)
  const int col   = lane & 15;
  const int quad  = lane >> 4;
  const int h     = 16 * cg + col;
  const unsigned short* W_ih = g_wsmall + OFF_WIH;
  const unsigned short* W_hh = g_wsmall + OFF_WHH;

  const float br  = b2f(g_wsmall[OFF_BIH + h])       + b2f(g_wsmall[OFF_BHH + h]);
  const float bz  = b2f(g_wsmall[OFF_BIH + 128 + h]) + b2f(g_wsmall[OFF_BHH + 128 + h]);
  const float bn  = b2f(g_wsmall[OFF_BIH + 256 + h]);
  const float bh_ = b2f(g_wsmall[OFF_BHH + 256 + h]);

  bf16x8 bIHr[4], bHHr[4], bIHz[4], bHHz[4], bIHn[4], bHHn[4];
#pragma unroll
  for (int kk = 0; kk < 4; kk++) {
    const int ko = kk * 32 + quad * 8;
    bIHr[kk] = load_frag(W_ih + h * D_FEAT + ko);
    bHHr[kk] = load_frag(W_hh + h * D_FEAT + ko);
    bIHz[kk] = load_frag(W_ih + (128 + h) * D_FEAT + ko);
    bHHz[kk] = load_frag(W_hh + (128 + h) * D_FEAT + ko);
    bIHn[kk] = load_frag(W_ih + (256 + h) * D_FEAT + ko);
    bHHn[kk] = load_frag(W_hh + (256 + h) * D_FEAT + ko);
  }

  const int t0 = chunk * GCHUNK;
  for (int t = t0; t < t0 + GCHUNK; t++) {
    const int arow = t * 16 + col;
    bf16x8 ax[4], ac[4];
#pragma unroll
    for (int kk = 0; kk < 4; kk++) {
      ax[kk] = load_frag(g_xbf + arow * D_FEAT + kk * 32 + quad * 8);
      ac[kk] = load_frag(g_ctx + arow * D_FEAT + kk * 32 + quad * 8);
    }
    f32x4 racc, zacc, niacc, nhacc;
    racc[0]=br;  racc[1]=br;  racc[2]=br;  racc[3]=br;
    zacc[0]=bz;  zacc[1]=bz;  zacc[2]=bz;  zacc[3]=bz;
    niacc[0]=bn; niacc[1]=bn; niacc[2]=bn; niacc[3]=bn;
    nhacc[0]=bh_; nhacc[1]=bh_; nhacc[2]=bh_; nhacc[3]=bh_;
#pragma unroll
    for (int kk = 0; kk < 4; kk++) {
      racc  = __builtin_amdgcn_mfma_f32_16x16x32_bf16(ac[kk], bIHr[kk], racc, 0, 0, 0);
      racc  = __builtin_amdgcn_mfma_f32_16x16x32_bf16(ax[kk], bHHr[kk], racc, 0, 0, 0);
      zacc  = __builtin_amdgcn_mfma_f32_16x16x32_bf16(ac[kk], bIHz[kk], zacc, 0, 0, 0);
      zacc  = __builtin_amdgcn_mfma_f32_16x16x32_bf16(ax[kk], bHHz[kk], zacc, 0, 0, 0);
      niacc = __builtin_amdgcn_mfma_f32_16x16x32_bf16(ac[kk], bIHn[kk], niacc, 0, 0, 0);
      nhacc = __builtin_amdgcn_mfma_f32_16x16x32_bf16(ax[kk], bHHn[kk], nhacc, 0, 0, 0);
    }
#pragma unroll
    for (int r = 0; r < 4; r++) {
      const int vrow = t * 16 + quad * 4 + r;
      const float rg = 1.f / (1.f + __expf(-racc[r]));
      const float zg = 1.f / (1.f + __expf(-zacc[r]));
      const float n  = tanhf(niacc[r] + rg * nhacc[r]);
      const float xv = b2f(g_xbf[vrow * D_FEAT + h]);
      const float hn = (1.f - zg) * n + zg * xv;
      out[vrow * D_FEAT + h] = (hn < 0.f) ? 0.f : hn;  // relu; NaN passes (canary)
    }
  }
}

// ---------------- launch ------------------------------------------------------
extern "C" void kernel_launch(void* const* d_in, const int* in_sizes, int n_in,
                              void* d_out, int out_size, void* d_ws, size_t ws_size,
                              hipStream_t stream)
{
  (void)d_ws; (void)ws_size; (void)out_size;

  // resolve inputs by element count (same-size pairs keep dict order)
  int ix = -1, iWe = -1, ibe = -1, iWp = -1, ibp = -1,
      iWih = -1, iWhh = -1, ibih = -1, ibhh = -1, isrc = -1, idst = -1;
  for (int i = 0; i < n_in; i++) {
    const int s = in_sizes[i];
    if      (s == 6400000) ix = i;
    else if (s == 256)     iWe = i;
    else if (s == 1)       ibe = i;
    else if (s == 16384)   iWp = i;
    else if (s == 128)     ibp = i;
    else if (s == 49152)   { if (iWih < 0) iWih = i; else iWhh = i; }
    else if (s == 384)     { if (ibih < 0) ibih = i; else ibhh = i; }
    else if (s == 800000)  { if (isrc < 0) isrc = i; else idst = i; }
  }
  if (ix < 0 || iWe < 0 || ibe < 0 || iWp < 0 || ibp < 0 || iWih < 0 ||
      iWhh < 0 || ibih < 0 || ibhh < 0 || isrc < 0 || idst < 0) {
    ix = 0; iWe = 1; ibe = 2; iWp = 3; ibp = 4;           // dict-order fallback
    iWih = 5; iWhh = 6; ibih = 7; ibhh = 8; isrc = 9; idst = 10;
  }

  const int* src = (const int*)d_in[isrc];
  const int* dst = (const int*)d_in[idst];
  float* out = (float*)d_out;

  probe_zero_kernel<<<1 + SCAN_BLOCKS, 256, 0, stream>>>((const unsigned int*)d_in[ix]);
  conv_hist_kernel<<<CONV_X_BLOCKS + CONV_S_BLOCKS + HIST_BLOCKS, 256, 0, stream>>>(
      d_in[ix], dst,
      d_in[iWe], d_in[iWp], d_in[iWih], d_in[iWhh],
      d_in[ibe], d_in[ibp], d_in[ibih], d_in[ibhh]);
  pdps_scan_a_kernel<<<NPW_BLOCKS + SCAN_BLOCKS, 256, 0, stream>>>();
  scan_b_kernel<<<1, 256, 0, stream>>>();
  scan_c_kernel<<<SCAN_BLOCKS, 256, 0, stream>>>();
  edge_scatter_kernel<<<E_EDGES / 256, 256, 0, stream>>>(src, dst, E_EDGES);
  agg_proj_kernel<<<NTILE, 1024, 0, stream>>>();
  gru_kernel<<<WS_BLOCKS, 256, 0, stream>>>(out);
}

// Round 16
// 265.223 us; speedup vs baseline: 1.0833x; 1.0833x over previous
//
#include <hip/hip_runtime.h>
#include <hip/hip_bf16.h>

// GNN attention layer. V=50000, E=800000, D=H=128. Inputs f32, OUTPUT f32.
//
// R16: revert R15's fusion shuffle (regressed: conv serialized ahead of hist,
// no overlap). Back to R14 shell (266 us) + two changes:
//  - hist: 4 edges/thread, 4 independent returning atomics in flight (tests
//    whether the constant ~60 us histogram is latency- or throughput-bound).
//  - scan_c deleted: scatter/agg add g_blockoff[v>>8] inline (one less launch).
// agg stays 4-deep (proven 60 us); conv/zero/pdps placement = R14.

#define V_NODES 50000
#define E_EDGES 800000
#define D_FEAT  128
#define NTILE   3125          // V/16
#define SCAN_BLOCKS 196       // ceil(50000/256)
#define GCHUNK  5             // tiles per wave-task (gru, pd/ps)
#define NP_TASKS 625
#define NPW_BLOCKS 157        // ceil(625/4)
#define HB4     782           // ceil(800000/1024) hist blocks (4 edges/thread)
#define WS_BLOCKS 1250        // gru: 5000 wave-tasks / 4 per block
#define AGG_STRIDE 132        // LDS row stride (elements)

typedef short bf16x8 __attribute__((ext_vector_type(8)));  // 8 bf16 in 4 VGPRs
typedef float f32x4  __attribute__((ext_vector_type(4)));
typedef unsigned short u16x4 __attribute__((ext_vector_type(4)));

// small-tensor bf16 pool element offsets
#define OFF_WEDGE 0
#define OFF_WPROJ 256
#define OFF_WIH   16640
#define OFF_WHH   65792
#define OFF_BEDGE 114944
#define OFF_BPROJ 114945
#define OFF_BIH   115073
#define OFF_BHH   115457
#define SMALL_TOTAL 115841
#define CONV_X_BLOCKS   6250   // 1.6M u16x4 / 256
#define ZERO_BLOCKS     196
#define CONV_S_BLOCKS   453

// ---- device-global scratch (~27 MB; immune to ws_size) ----
__device__ int   g_is_bf16;
__device__ float g_pd[V_NODES];
__device__ float g_ps[V_NODES];
__device__ int   g_counts[V_NODES];
__device__ int   g_row_off[V_NODES + 1];   // block-LOCAL exclusive prefix
__device__ int   g_blocksum[SCAN_BLOCKS];
__device__ int   g_blockoff[SCAN_BLOCKS];
__device__ int   g_rank[E_EDGES];
__device__ __attribute__((aligned(16))) int2 g_s_pair[E_EDGES];  // {src, bits(w)}
__device__ __attribute__((aligned(16))) unsigned short g_xbf[V_NODES * D_FEAT];
__device__ __attribute__((aligned(16))) unsigned short g_ctx[V_NODES * D_FEAT];
__device__ __attribute__((aligned(16))) unsigned short g_wsmall[SMALL_TOTAL + 15];

static __device__ __forceinline__ float b2f(unsigned short u) {
  union { unsigned int i; float f; } v; v.i = ((unsigned int)u) << 16; return v.f;
}
static __device__ __forceinline__ unsigned short f2b(float f) {
  unsigned int i = __float_as_uint(f);
  unsigned int r = (i + 0x7FFFu + ((i >> 16) & 1u)) >> 16;  // RNE (NaN stays NaN)
  return (unsigned short)r;
}
static __device__ __forceinline__ bf16x8 load_frag(const unsigned short* p) {
  return *reinterpret_cast<const bf16x8*>(p);  // 16B-aligned vector load
}
static __device__ __forceinline__ bf16x8 lds_frag(const unsigned short* p) {
  const uint2 lo = *reinterpret_cast<const uint2*>(p);
  const uint2 hi = *reinterpret_cast<const uint2*>(p + 4);
  uint4 u; u.x = lo.x; u.y = lo.y; u.z = hi.x; u.w = hi.y;
  return __builtin_bit_cast(bf16x8, u);
}

// ---------------- P: dtype probe on x ----------------------------------------
__global__ void probe_kernel(const unsigned int* __restrict__ x)
{
  __shared__ int cnt;
  if (threadIdx.x == 0) cnt = 0;
  __syncthreads();
  const unsigned int w  = x[threadIdx.x];
  const unsigned int lo = w & 0xFFFFu;
  const unsigned int ex = (lo >> 7) & 0xFFu;
  if (lo != 0u && ex >= 118u && ex <= 132u) atomicAdd(&cnt, 1);
  __syncthreads();
  if (threadIdx.x == 0) g_is_bf16 = (cnt >= 200) ? 1 : 0;
}

// ---------------- C: fused convert-x | zero-counts | convert-smalls ----------
__global__ void conv_fused_kernel(
    const void* __restrict__ x,
    const void* p0, const void* p1, const void* p2, const void* p3,
    const void* p4, const void* p5, const void* p6, const void* p7)
{
  const int b = blockIdx.x;
  if (b < CONV_X_BLOCKS) {
    const int t = b * 256 + threadIdx.x;
    if (g_is_bf16) {
      reinterpret_cast<u16x4*>(g_xbf)[t] = reinterpret_cast<const u16x4*>(x)[t];
    } else {
      const float4 v = reinterpret_cast<const float4*>(x)[t];
      u16x4 o; o.x = f2b(v.x); o.y = f2b(v.y); o.z = f2b(v.z); o.w = f2b(v.w);
      reinterpret_cast<u16x4*>(g_xbf)[t] = o;
    }
  } else if (b < CONV_X_BLOCKS + ZERO_BLOCKS) {
    const int i = (b - CONV_X_BLOCKS) * 256 + threadIdx.x;
    if (i < V_NODES) g_counts[i] = 0;
  } else {
    const int i = (b - CONV_X_BLOCKS - ZERO_BLOCKS) * 256 + threadIdx.x;
    if (i >= SMALL_TOTAL) return;
    const int offs[9] = {OFF_WEDGE, OFF_WPROJ, OFF_WIH, OFF_WHH,
                         OFF_BEDGE, OFF_BPROJ, OFF_BIH, OFF_BHH, SMALL_TOTAL};
    const void* ps[8] = {p0, p1, p2, p3, p4, p5, p6, p7};
    int r = 0;
#pragma unroll
    for (int k = 0; k < 8; k++) if (i >= offs[k]) r = k;
    const int j = i - offs[r];
    g_wsmall[i] = g_is_bf16
        ? reinterpret_cast<const unsigned short*>(ps[r])[j]
        : f2b(reinterpret_cast<const float*>(ps[r])[j]);
  }
}

// ---------------- K1: hist (4 edges/thread, 4 atomics in flight) + pd/ps -----
__global__ __launch_bounds__(256, 2) void np_hist_kernel(const int* __restrict__ dst)
{
  const int b = blockIdx.x;
  if (b < HB4) {                             // ---- histogram + rank part ----
    const int base = b * 1024 + threadIdx.x;
    int d[4];
#pragma unroll
    for (int k = 0; k < 4; k++) {
      const int e = base + k * 256;
      d[k] = (e < E_EDGES) ? dst[e] : -1;
    }
    int r[4];
#pragma unroll
    for (int k = 0; k < 4; k++)
      if (d[k] >= 0) r[k] = atomicAdd(&g_counts[d[k]], 1);
#pragma unroll
    for (int k = 0; k < 4; k++) {
      const int e = base + k * 256;
      if (d[k] >= 0) g_rank[e] = r[k];
    }
    return;
  }
  // ---- pd/ps part ----
  const int g    = (b - HB4) * 4 + (threadIdx.x >> 6);
  if (g >= NP_TASKS) return;
  const int lane = threadIdx.x & 63;
  const int col  = lane & 15;
  const int quad = lane >> 4;

  bf16x8 be[4];
#pragma unroll
  for (int kk = 0; kk < 4; kk++) { be[kk] = bf16x8{0,0,0,0,0,0,0,0}; }
  if (col < 2) {
#pragma unroll
    for (int kk = 0; kk < 4; kk++)
      be[kk] = load_frag(g_wsmall + OFF_WEDGE + col * D_FEAT + kk * 32 + quad * 8);
  }
  const int t0 = g * GCHUNK;
  for (int t = t0; t < t0 + GCHUNK; t++) {
    const int arow = t * 16 + col;
    bf16x8 a[4];
#pragma unroll
    for (int kk = 0; kk < 4; kk++)
      a[kk] = load_frag(g_xbf + arow * D_FEAT + kk * 32 + quad * 8);
    f32x4 acce; acce[0]=0.f; acce[1]=0.f; acce[2]=0.f; acce[3]=0.f;
#pragma unroll
    for (int kk = 0; kk < 4; kk++)
      acce = __builtin_amdgcn_mfma_f32_16x16x32_bf16(a[kk], be[kk], acce, 0, 0, 0);
    if (col == 0) {
#pragma unroll
      for (int r = 0; r < 4; r++) g_pd[t * 16 + quad * 4 + r] = acce[r];
    } else if (col == 1) {
#pragma unroll
      for (int r = 0; r < 4; r++) g_ps[t * 16 + quad * 4 + r] = acce[r];
    }
  }
}

// ---------------- K3a: block-local exclusive scan ----------------------------
__global__ __launch_bounds__(256) void scan_a_kernel()
{
  __shared__ int lds[256];
  const int b = blockIdx.x, t = threadIdx.x;
  const int idx = b * 256 + t;
  const int v = (idx < V_NODES) ? g_counts[idx] : 0;
  lds[t] = v;
  __syncthreads();
  for (int off = 1; off < 256; off <<= 1) {
    int tmp = (t >= off) ? lds[t - off] : 0;
    __syncthreads();
    lds[t] += tmp;
    __syncthreads();
  }
  if (idx < V_NODES) g_row_off[idx] = lds[t] - v;   // LOCAL exclusive prefix
  if (t == 255) g_blocksum[b] = lds[255];
}

// ---------------- K3b: scan the 196 block totals ------------------------------
__global__ __launch_bounds__(256) void scan_b_kernel()
{
  __shared__ int lds[256];
  const int t = threadIdx.x;
  const int v = (t < SCAN_BLOCKS) ? g_blocksum[t] : 0;
  lds[t] = v;
  __syncthreads();
  for (int off = 1; off < 256; off <<= 1) {
    int tmp = (t >= off) ? lds[t - off] : 0;
    __syncthreads();
    lds[t] += tmp;
    __syncthreads();
  }
  if (t < SCAN_BLOCKS) g_blockoff[t] = lds[t] - v;
}

// ---------------- K4: edge scatter — atomic-free, blockoff inline ------------
__global__ void edge_scatter_kernel(
    const int* __restrict__ src, const int* __restrict__ dst, int E)
{
  int e = blockIdx.x * blockDim.x + threadIdx.x;
  if (e >= E) return;
  const int d = dst[e], sn = src[e];
  float logit = g_pd[d] + g_ps[sn] + b2f(g_wsmall[OFF_BEDGE]);
  logit = (logit >= 0.f) ? logit : 0.01f * logit;           // LeakyReLU(0.01)
  const float w = __expf(logit);                            // no max-sub: cancels
  const int pos = g_row_off[d] + g_blockoff[d >> 8] + g_rank[e];
  g_s_pair[pos] = make_int2(sn, __float_as_int(w));
}

// ---------------- K5: aggregate (node/wave, 4-deep) + proj + elu -> ctx ------
__global__ __launch_bounds__(1024) void agg_proj_kernel()
{
  __shared__ unsigned short s_agg[16 * AGG_STRIDE];   // 4224 B
  __shared__ int s_empty[16];
  const int wave = threadIdx.x >> 6;                  // 16 waves = 16 nodes
  const int lane = threadIdx.x & 63;
  const int tile = blockIdx.x;                        // 16-node tile, [0,3125)

  // ---- phase 1: softmax-weighted x-gather, ONE node per wave ----
  {
    const int v = tile * 16 + wave;
    const int beg = g_row_off[v] + g_blockoff[v >> 8];
    const int end = (v + 1 < V_NODES)
                        ? g_row_off[v + 1] + g_blockoff[(v + 1) >> 8]
                        : E_EDGES;
    float accx = 0.f, accy = 0.f, ssum = 0.f;
    int i = beg;
    for (; i + 4 <= end; i += 4) {       // 4 gathers in flight
      const int2 q0 = g_s_pair[i],     q1 = g_s_pair[i + 1],
                 q2 = g_s_pair[i + 2], q3 = g_s_pair[i + 3];
      const float w0 = __int_as_float(q0.y), w1 = __int_as_float(q1.y),
                  w2 = __int_as_float(q2.y), w3 = __int_as_float(q3.y);
      const unsigned int p0 = *reinterpret_cast<const unsigned int*>(g_xbf + q0.x * D_FEAT + lane * 2);
      const unsigned int p1 = *reinterpret_cast<const unsigned int*>(g_xbf + q1.x * D_FEAT + lane * 2);
      const unsigned int p2 = *reinterpret_cast<const unsigned int*>(g_xbf + q2.x * D_FEAT + lane * 2);
      const unsigned int p3 = *reinterpret_cast<const unsigned int*>(g_xbf + q3.x * D_FEAT + lane * 2);
      ssum += (w0 + w1) + (w2 + w3);
      accx += w0 * b2f((unsigned short)(p0 & 0xFFFFu)) + w1 * b2f((unsigned short)(p1 & 0xFFFFu))
            + w2 * b2f((unsigned short)(p2 & 0xFFFFu)) + w3 * b2f((unsigned short)(p3 & 0xFFFFu));
      accy += w0 * b2f((unsigned short)(p0 >> 16)) + w1 * b2f((unsigned short)(p1 >> 16))
            + w2 * b2f((unsigned short)(p2 >> 16)) + w3 * b2f((unsigned short)(p3 >> 16));
    }
    for (; i < end; i++) {
      const int2 q = g_s_pair[i];
      const float w = __int_as_float(q.y);
      ssum += w;
      const unsigned int pair =
          *reinterpret_cast<const unsigned int*>(g_xbf + q.x * D_FEAT + lane * 2);
      accx += w * b2f((unsigned short)(pair & 0xFFFFu));
      accy += w * b2f((unsigned short)(pair >> 16));
    }
    const float inv = (end > beg) ? (1.0f / ssum) : 0.0f;
    const unsigned int packed =
        ((unsigned int)f2b(accy * inv) << 16) | (unsigned int)f2b(accx * inv);
    *reinterpret_cast<unsigned int*>(s_agg + wave * AGG_STRIDE + lane * 2) = packed;
    if (lane == 0) s_empty[wave] = (end > beg) ? 0 : 1;
  }
  __syncthreads();

  // ---- phase 2: ctx = elu(agg @ Wproj.T + b_proj); waves 0..7, one cg each --
  if (wave < 8) {
    const int col  = lane & 15;
    const int quad = lane >> 4;
    bf16x8 a[4];
#pragma unroll
    for (int kk = 0; kk < 4; kk++)
      a[kk] = lds_frag(s_agg + col * AGG_STRIDE + kk * 32 + quad * 8);
    const int h  = 16 * wave + col;
    const float bp = b2f(g_wsmall[OFF_BPROJ + h]);
    f32x4 acc; acc[0]=bp; acc[1]=bp; acc[2]=bp; acc[3]=bp;
#pragma unroll
    for (int kk = 0; kk < 4; kk++) {
      bf16x8 bw = load_frag(g_wsmall + OFF_WPROJ + h * D_FEAT + kk * 32 + quad * 8);
      acc = __builtin_amdgcn_mfma_f32_16x16x32_bf16(a[kk], bw, acc, 0, 0, 0);
    }
#pragma unroll
    for (int r = 0; r < 4; r++) {
      const int n = quad * 4 + r;
      float v = acc[r];
      v = (v > 0.f) ? v : (__expf(v) - 1.f);            // elu
      if (s_empty[n]) v = 0.f;                          // empty segment -> ctx 0
      g_ctx[(tile * 16 + n) * D_FEAT + h] = f2b(v);
    }
  }
}

// ---------------- K6: GRU weight-stationary (bf16 residual) ------------------
__global__ __launch_bounds__(256, 2) void gru_kernel(float* __restrict__ out)
{
  const int g     = blockIdx.x * 4 + (threadIdx.x >> 6);
  const int lane  = threadIdx.x & 63;
  const int cg    = g & 7;
  const int chunk = g >> 3;                  // [0, 625)
  const int col   = lane & 15;
  const int quad  = lane >> 4;
  const int h     = 16 * cg + col;
  const unsigned short* W_ih = g_wsmall + OFF_WIH;
  const unsigned short* W_hh = g_wsmall + OFF_WHH;

  const float br  = b2f(g_wsmall[OFF_BIH + h])       + b2f(g_wsmall[OFF_BHH + h]);
  const float bz  = b2f(g_wsmall[OFF_BIH + 128 + h]) + b2f(g_wsmall[OFF_BHH + 128 + h]);
  const float bn  = b2f(g_wsmall[OFF_BIH + 256 + h]);
  const float bh_ = b2f(g_wsmall[OFF_BHH + 256 + h]);

  bf16x8 bIHr[4], bHHr[4], bIHz[4], bHHz[4], bIHn[4], bHHn[4];
#pragma unroll
  for (int kk = 0; kk < 4; kk++) {
    const int ko = kk * 32 + quad * 8;
    bIHr[kk] = load_frag(W_ih + h * D_FEAT + ko);
    bHHr[kk] = load_frag(W_hh + h * D_FEAT + ko);
    bIHz[kk] = load_frag(W_ih + (128 + h) * D_FEAT + ko);
    bHHz[kk] = load_frag(W_hh + (128 + h) * D_FEAT + ko);
    bIHn[kk] = load_frag(W_ih + (256 + h) * D_FEAT + ko);
    bHHn[kk] = load_frag(W_hh + (256 + h) * D_FEAT + ko);
  }

  const int t0 = chunk * GCHUNK;
  for (int t = t0; t < t0 + GCHUNK; t++) {
    const int arow = t * 16 + col;
    bf16x8 ax[4], ac[4];
#pragma unroll
    for (int kk = 0; kk < 4; kk++) {
      ax[kk] = load_frag(g_xbf + arow * D_FEAT + kk * 32 + quad * 8);
      ac[kk] = load_frag(g_ctx + arow * D_FEAT + kk * 32 + quad * 8);
    }
    f32x4 racc, zacc, niacc, nhacc;
    racc[0]=br;  racc[1]=br;  racc[2]=br;  racc[3]=br;
    zacc[0]=bz;  zacc[1]=bz;  zacc[2]=bz;  zacc[3]=bz;
    niacc[0]=bn; niacc[1]=bn; niacc[2]=bn; niacc[3]=bn;
    nhacc[0]=bh_; nhacc[1]=bh_; nhacc[2]=bh_; nhacc[3]=bh_;
#pragma unroll
    for (int kk = 0; kk < 4; kk++) {
      racc  = __builtin_amdgcn_mfma_f32_16x16x32_bf16(ac[kk], bIHr[kk], racc, 0, 0, 0);
      racc  = __builtin_amdgcn_mfma_f32_16x16x32_bf16(ax[kk], bHHr[kk], racc, 0, 0, 0);
      zacc  = __builtin_amdgcn_mfma_f32_16x16x32_bf16(ac[kk], bIHz[kk], zacc, 0, 0, 0);
      zacc  = __builtin_amdgcn_mfma_f32_16x16x32_bf16(ax[kk], bHHz[kk], zacc, 0, 0, 0);
      niacc = __builtin_amdgcn_mfma_f32_16x16x32_bf16(ac[kk], bIHn[kk], niacc, 0, 0, 0);
      nhacc = __builtin_amdgcn_mfma_f32_16x16x32_bf16(ax[kk], bHHn[kk], nhacc, 0, 0, 0);
    }
#pragma unroll
    for (int r = 0; r < 4; r++) {
      const int vrow = t * 16 + quad * 4 + r;
      const float rg = 1.f / (1.f + __expf(-racc[r]));
      const float zg = 1.f / (1.f + __expf(-zacc[r]));
      const float n  = tanhf(niacc[r] + rg * nhacc[r]);
      const float xv = b2f(g_xbf[vrow * D_FEAT + h]);
      const float hn = (1.f - zg) * n + zg * xv;
      out[vrow * D_FEAT + h] = (hn < 0.f) ? 0.f : hn;  // relu; NaN passes (canary)
    }
  }
}

// ---------------- launch ------------------------------------------------------
extern "C" void kernel_launch(void* const* d_in, const int* in_sizes, int n_in,
                              void* d_out, int out_size, void* d_ws, size_t ws_size,
                              hipStream_t stream)
{
  (void)d_ws; (void)ws_size; (void)out_size;

  // resolve inputs by element count (same-size pairs keep dict order)
  int ix = -1, iWe = -1, ibe = -1, iWp = -1, ibp = -1,
      iWih = -1, iWhh = -1, ibih = -1, ibhh = -1, isrc = -1, idst = -1;
  for (int i = 0; i < n_in; i++) {
    const int s = in_sizes[i];
    if      (s == 6400000) ix = i;
    else if (s == 256)     iWe = i;
    else if (s == 1)       ibe = i;
    else if (s == 16384)   iWp = i;
    else if (s == 128)     ibp = i;
    else if (s == 49152)   { if (iWih < 0) iWih = i; else iWhh = i; }
    else if (s == 384)     { if (ibih < 0) ibih = i; else ibhh = i; }
    else if (s == 800000)  { if (isrc < 0) isrc = i; else idst = i; }
  }
  if (ix < 0 || iWe < 0 || ibe < 0 || iWp < 0 || ibp < 0 || iWih < 0 ||
      iWhh < 0 || ibih < 0 || ibhh < 0 || isrc < 0 || idst < 0) {
    ix = 0; iWe = 1; ibe = 2; iWp = 3; ibp = 4;           // dict-order fallback
    iWih = 5; iWhh = 6; ibih = 7; ibhh = 8; isrc = 9; idst = 10;
  }

  const int* src = (const int*)d_in[isrc];
  const int* dst = (const int*)d_in[idst];
  float* out = (float*)d_out;

  probe_kernel<<<1, 256, 0, stream>>>((const unsigned int*)d_in[ix]);
  conv_fused_kernel<<<CONV_X_BLOCKS + ZERO_BLOCKS + CONV_S_BLOCKS, 256, 0, stream>>>(
      d_in[ix],
      d_in[iWe], d_in[iWp], d_in[iWih], d_in[iWhh],
      d_in[ibe], d_in[ibp], d_in[ibih], d_in[ibhh]);
  np_hist_kernel<<<HB4 + NPW_BLOCKS, 256, 0, stream>>>(dst);
  scan_a_kernel<<<SCAN_BLOCKS, 256, 0, stream>>>();
  scan_b_kernel<<<1, 256, 0, stream>>>();
  edge_scatter_kernel<<<E_EDGES / 256, 256, 0, stream>>>(src, dst, E_EDGES);
  agg_proj_kernel<<<NTILE, 1024, 0, stream>>>();
  gru_kernel<<<WS_BLOCKS, 256, 0, stream>>>(out);
}